// Round 2
// baseline (4249.287 us; speedup 1.0000x reference)
//
#include <hip/hip_runtime.h>
#include <hip/hip_bf16.h>
#include <type_traits>

using bf16 = __hip_bfloat16;

static constexpr int BG   = 16384;          // graphs
static constexpr int NPG  = 11;             // nodes per graph
static constexpr int NTOT = BG * NPG;       // 180224 nodes
static constexpr int EDG  = NTOT * 8;       // 1441792 edges
static constexpr int CHG  = 2048;           // graphs per layer-2 chunk
static constexpr int CHR  = CHG * NPG;      // 22528 rows per chunk (divisible by 64)

__device__ __forceinline__ float toF(float x) { return x; }
__device__ __forceinline__ float toF(bf16 x)  { return __bfloat162float(x); }
__device__ __forceinline__ void  stC(float* p, float v) { *p = v; }
__device__ __forceinline__ void  stC(bf16* p, float v)  { *p = __float2bfloat16(v); }

// ---------------------------------------------------------------------------
// Generic tiled GEMM: C[M,N] = A[M,K] @ B[K,N], B row-major fp32 weights.
// 64x64 tile, BK=32, 256 threads, 4x4 micro-tile. M%64==0, N%64==0, K%32==0.
// ---------------------------------------------------------------------------
template<typename TA, typename TC>
__global__ __launch_bounds__(256) void gemm_nn(const TA* __restrict__ A,
                                               const float* __restrict__ Bw,
                                               TC* __restrict__ C,
                                               int N, int K) {
  __shared__ float As[32][68];   // [k][row], padded
  __shared__ float Bs[32][68];   // [k][col], padded
  const int tid = threadIdx.x;
  const int tx = tid & 15, ty = tid >> 4;
  const int row0 = blockIdx.y * 64;
  const int col0 = blockIdx.x * 64;
  float acc[4][4] = {{0.f, 0.f, 0.f, 0.f}, {0.f, 0.f, 0.f, 0.f},
                     {0.f, 0.f, 0.f, 0.f}, {0.f, 0.f, 0.f, 0.f}};
  const int r  = tid >> 3;          // 0..31
  const int kv = (tid & 7) * 4;     // 0..28
  const int bk = tid >> 4;          // 0..15
  const int jv = (tid & 15) * 4;    // 0..60

  for (int k0 = 0; k0 < K; k0 += 32) {
    #pragma unroll
    for (int rr = 0; rr < 64; rr += 32) {
      const TA* ap = A + (size_t)(row0 + r + rr) * K + (k0 + kv);
      float v0, v1, v2, v3;
      if constexpr (std::is_same<TA, float>::value) {
        float4 a4 = *(const float4*)ap;
        v0 = a4.x; v1 = a4.y; v2 = a4.z; v3 = a4.w;
      } else {
        v0 = toF(ap[0]); v1 = toF(ap[1]); v2 = toF(ap[2]); v3 = toF(ap[3]);
      }
      As[kv + 0][r + rr] = v0;
      As[kv + 1][r + rr] = v1;
      As[kv + 2][r + rr] = v2;
      As[kv + 3][r + rr] = v3;
    }
    #pragma unroll
    for (int kq = 0; kq < 32; kq += 16) {
      const float* bp = Bw + (size_t)(k0 + bk + kq) * N + (col0 + jv);
      float4 b4 = *(const float4*)bp;
      *(float4*)&Bs[bk + kq][jv] = b4;
    }
    __syncthreads();
    #pragma unroll
    for (int kk = 0; kk < 32; ++kk) {
      float4 a = *(const float4*)&As[kk][ty * 4];
      float4 b = *(const float4*)&Bs[kk][tx * 4];
      acc[0][0] += a.x * b.x; acc[0][1] += a.x * b.y; acc[0][2] += a.x * b.z; acc[0][3] += a.x * b.w;
      acc[1][0] += a.y * b.x; acc[1][1] += a.y * b.y; acc[1][2] += a.y * b.z; acc[1][3] += a.y * b.w;
      acc[2][0] += a.z * b.x; acc[2][1] += a.z * b.y; acc[2][2] += a.z * b.z; acc[2][3] += a.z * b.w;
      acc[3][0] += a.w * b.x; acc[3][1] += a.w * b.y; acc[3][2] += a.w * b.z; acc[3][3] += a.w * b.w;
    }
    __syncthreads();
  }
  #pragma unroll
  for (int i = 0; i < 4; ++i) {
    TC* cp = C + (size_t)(row0 + ty * 4 + i) * N + (col0 + tx * 4);
    stC(cp + 0, acc[i][0]); stC(cp + 1, acc[i][1]);
    stC(cp + 2, acc[i][2]); stC(cp + 3, acc[i][3]);
  }
}

// ---------------------------------------------------------------------------
// LSTM step GEMM: gates[16384,1024] = [x_t | h] (K=512) @ [Wih | Whh]^T
// x_t rows live at feature[b*2816 + t*256 + k]; weights are [1024,256] (B^T).
// ---------------------------------------------------------------------------
__global__ __launch_bounds__(256) void gemm_lstm(const float* __restrict__ feat,
                                                 const float* __restrict__ h,
                                                 const float* __restrict__ Wih,
                                                 const float* __restrict__ Whh,
                                                 float* __restrict__ gates,
                                                 int t) {
  __shared__ float As[32][68];
  __shared__ float Bs[32][68];
  const int tid = threadIdx.x;
  const int tx = tid & 15, ty = tid >> 4;
  const int row0 = blockIdx.y * 64;
  const int col0 = blockIdx.x * 64;
  float acc[4][4] = {{0.f, 0.f, 0.f, 0.f}, {0.f, 0.f, 0.f, 0.f},
                     {0.f, 0.f, 0.f, 0.f}, {0.f, 0.f, 0.f, 0.f}};
  const int r  = tid >> 3;          // 0..31
  const int kv = (tid & 7) * 4;     // 0..28

  for (int k0 = 0; k0 < 512; k0 += 32) {
    const float* Abase; int astride; int koff; const float* Wbase;
    if (k0 < 256) { Abase = feat + t * 256; astride = NPG * 256; koff = k0;       Wbase = Wih; }
    else          { Abase = h;              astride = 256;       koff = k0 - 256; Wbase = Whh; }
    #pragma unroll
    for (int rr = 0; rr < 64; rr += 32) {
      const float* ap = Abase + (size_t)(row0 + r + rr) * astride + koff + kv;
      float4 a4 = *(const float4*)ap;
      As[kv + 0][r + rr] = a4.x;
      As[kv + 1][r + rr] = a4.y;
      As[kv + 2][r + rr] = a4.z;
      As[kv + 3][r + rr] = a4.w;
    }
    #pragma unroll
    for (int jj = 0; jj < 64; jj += 32) {
      const float* bp = Wbase + (size_t)(col0 + r + jj) * 256 + koff + kv;
      float4 b4 = *(const float4*)bp;
      Bs[kv + 0][r + jj] = b4.x;
      Bs[kv + 1][r + jj] = b4.y;
      Bs[kv + 2][r + jj] = b4.z;
      Bs[kv + 3][r + jj] = b4.w;
    }
    __syncthreads();
    #pragma unroll
    for (int kk = 0; kk < 32; ++kk) {
      float4 a = *(const float4*)&As[kk][ty * 4];
      float4 b = *(const float4*)&Bs[kk][tx * 4];
      acc[0][0] += a.x * b.x; acc[0][1] += a.x * b.y; acc[0][2] += a.x * b.z; acc[0][3] += a.x * b.w;
      acc[1][0] += a.y * b.x; acc[1][1] += a.y * b.y; acc[1][2] += a.y * b.z; acc[1][3] += a.y * b.w;
      acc[2][0] += a.z * b.x; acc[2][1] += a.z * b.y; acc[2][2] += a.z * b.z; acc[2][3] += a.z * b.w;
      acc[3][0] += a.w * b.x; acc[3][1] += a.w * b.y; acc[3][2] += a.w * b.z; acc[3][3] += a.w * b.w;
    }
    __syncthreads();
  }
  #pragma unroll
  for (int i = 0; i < 4; ++i) {
    float* cp = gates + (size_t)(row0 + ty * 4 + i) * 1024 + (col0 + tx * 4);
    cp[0] = acc[i][0]; cp[1] = acc[i][1]; cp[2] = acc[i][2]; cp[3] = acc[i][3];
  }
}

// gates -> (c,h) update. PyTorch gate order i,f,g,o.
__global__ __launch_bounds__(256) void lstm_pointwise(const float* __restrict__ gates,
                                                      const float* __restrict__ bih,
                                                      const float* __restrict__ bhh,
                                                      float* __restrict__ h,
                                                      float* __restrict__ c) {
  const int idx = blockIdx.x * 256 + threadIdx.x;   // B*256 threads
  const int b = idx >> 8, u = idx & 255;
  const float* gp = gates + (size_t)b * 1024;
  float gi = gp[u]       + bih[u]       + bhh[u];
  float gf = gp[256 + u] + bih[256 + u] + bhh[256 + u];
  float gg = gp[512 + u] + bih[512 + u] + bhh[512 + u];
  float go = gp[768 + u] + bih[768 + u] + bhh[768 + u];
  float si = 1.f / (1.f + __expf(-gi));
  float sf = 1.f / (1.f + __expf(-gf));
  float so = 1.f / (1.f + __expf(-go));
  float cn = sf * c[idx] + si * tanhf(gg);
  c[idx] = cn;
  h[idx] = so * tanhf(cn);
}

// out_ff[b,:2] = (h[b] @ Wf1 + bf1) @ Wf2 + bf2   (no activation; dropout=id)
__global__ __launch_bounds__(64) void ff_kernel(const float* __restrict__ h,
                                                const float* __restrict__ Wf1,
                                                const float* __restrict__ bf1,
                                                const float* __restrict__ Wf2,
                                                const float* __restrict__ bf2,
                                                float* __restrict__ ffout) {
  __shared__ float hrow[256];
  __shared__ float tmp[64];
  const int b = blockIdx.x, tid = threadIdx.x;
  for (int k = tid; k < 256; k += 64) hrow[k] = h[(size_t)b * 256 + k];
  __syncthreads();
  float acc = bf1[tid];
  #pragma unroll 8
  for (int k = 0; k < 256; ++k) acc += hrow[k] * Wf1[k * 64 + tid];
  tmp[tid] = acc;
  __syncthreads();
  if (tid < 2) {
    float o = bf2[tid];
    #pragma unroll
    for (int j = 0; j < 64; ++j) o += tmp[j] * Wf2[j * 2 + tid];
    ffout[(size_t)b * 2 + tid] = o;
  }
}

// ---------------- GCN graph-operator precompute ----------------
__global__ __launch_bounds__(256) void k_edge_deg(const int* __restrict__ src,
                                                  const int* __restrict__ dst,
                                                  float* __restrict__ odeg,
                                                  float* __restrict__ ideg) {
  const int e = blockIdx.x * 256 + threadIdx.x;
  atomicAdd(&odeg[src[e]], 1.0f);
  atomicAdd(&ideg[dst[e]], 1.0f);
}

__global__ __launch_bounds__(256) void k_norms(float* __restrict__ d) {
  const int i = blockIdx.x * 256 + threadIdx.x;   // covers sn and dn (2*NTOT)
  d[i] = rsqrtf(fmaxf(d[i], 1.0f));
}

// M_g[d][s] = dn[g*11+d] * count(s->d) * sn[g*11+s]
__global__ __launch_bounds__(256) void k_build_M(const int* __restrict__ src,
                                                 const int* __restrict__ dst,
                                                 const float* __restrict__ sn,
                                                 const float* __restrict__ dn,
                                                 float* __restrict__ Mg) {
  const int e = blockIdx.x * 256 + threadIdx.x;
  const int s = src[e], d = dst[e];
  const int gs = s / NPG;
  const int gd = d / NPG;           // gs == gd by construction
  const int ls = s - gs * NPG;
  const int ld = d - gd * NPG;
  atomicAdd(&Mg[(size_t)gd * 121 + ld * NPG + ls], sn[s] * dn[d]);
}

// X[g,d,:] = act( sum_s M_g[d][s] * Y[g,s,:] + bias )   (ACT 0=relu, 1=tanh)
// Column-exclusive per thread: safe when X aliases Y (in-place).
// gofs: global graph index offset for the Mg table.
template<int ACT>
__global__ __launch_bounds__(256) void k_mapply(const bf16* __restrict__ Y,
                                                const float* __restrict__ Mg,
                                                const float* __restrict__ bias,
                                                bf16* __restrict__ X,
                                                int gofs) {
  __shared__ float Ms[121];
  const int g = blockIdx.x, c = threadIdx.x;
  if (c < 121) Ms[c] = Mg[(size_t)(gofs + g) * 121 + c];
  float y[NPG];
  const bf16* yp = Y + (size_t)g * NPG * 256 + c;
  #pragma unroll
  for (int s = 0; s < NPG; ++s) y[s] = toF(yp[s * 256]);
  const float bc_ = bias[c];
  __syncthreads();
  bf16* xp = X + (size_t)g * NPG * 256 + c;
  #pragma unroll
  for (int d = 0; d < NPG; ++d) {
    float z = bc_;
    #pragma unroll
    for (int s = 0; s < NPG; ++s) z += Ms[d * NPG + s] * y[s];
    if (ACT == 0) z = fmaxf(z, 0.f); else z = tanhf(z);
    xp[d * 256] = __float2bfloat16(z);
  }
}

// Y3[N,8] = X[N,256] @ W3[256,8]
__global__ __launch_bounds__(256) void k_gemm3(const bf16* __restrict__ X,
                                               const float* __restrict__ W3,
                                               float* __restrict__ Y3) {
  __shared__ float W3s[2048];
  const int tid = threadIdx.x;
  for (int i = tid; i < 2048; i += 256) W3s[i] = W3[i];
  __syncthreads();
  const int r = tid >> 3, j = tid & 7;
  const int row = blockIdx.x * 32 + r;
  const bf16* xp = X + (size_t)row * 256;
  float acc = 0.f;
  #pragma unroll 4
  for (int k = 0; k < 256; ++k) acc += toF(xp[k]) * W3s[k * 8 + j];
  Y3[(size_t)row * 8 + j] = acc;
}

// layer3 M-apply + relu + mean over 11 nodes + classify + add LSTM ff output
__global__ __launch_bounds__(256) void k_final(const float* __restrict__ Y3,
                                               const float* __restrict__ Mg,
                                               const float* __restrict__ b3,
                                               const float* __restrict__ Wc,
                                               const float* __restrict__ bc,
                                               const float* __restrict__ ffout,
                                               float* __restrict__ out) {
  __shared__ float Ms[32][121];
  __shared__ float hg[32][8];
  const int tid = threadIdx.x;
  const int g0 = blockIdx.x * 32;
  for (int i = tid; i < 32 * 121; i += 256) Ms[i / 121][i % 121] = Mg[(size_t)g0 * 121 + i];
  const int gl = tid >> 3, j = tid & 7;
  const int g = g0 + gl;
  float y[NPG];
  #pragma unroll
  for (int s = 0; s < NPG; ++s) y[s] = Y3[((size_t)g * NPG + s) * 8 + j];
  __syncthreads();
  const float bj = b3[j];
  float accm = 0.f;
  #pragma unroll
  for (int d = 0; d < NPG; ++d) {
    float z = bj;
    #pragma unroll
    for (int s = 0; s < NPG; ++s) z += Ms[gl][d * NPG + s] * y[s];
    accm += fmaxf(z, 0.f);
  }
  hg[gl][j] = accm * (1.0f / 11.0f);
  __syncthreads();
  if (j < 2) {
    float o = bc[j];
    #pragma unroll
    for (int q = 0; q < 8; ++q) o += hg[gl][q] * Wc[q * 2 + j];
    out[(size_t)g * 2 + j] = o + ffout[(size_t)g * 2 + j];
  }
}

// ---------------------------------------------------------------------------
extern "C" void kernel_launch(void* const* d_in, const int* in_sizes, int n_in,
                              void* d_out, int out_size, void* d_ws, size_t ws_size,
                              hipStream_t stream) {
  (void)in_sizes; (void)n_in; (void)out_size; (void)ws_size;
  const float* feature = (const float*)d_in[0];
  const int*   src     = (const int*)d_in[1];
  const int*   dst     = (const int*)d_in[2];
  const float* W1  = (const float*)d_in[3];
  const float* b1  = (const float*)d_in[4];
  const float* W2  = (const float*)d_in[5];
  const float* b2  = (const float*)d_in[6];
  const float* W3  = (const float*)d_in[7];
  const float* b3  = (const float*)d_in[8];
  const float* Wih = (const float*)d_in[9];
  const float* Whh = (const float*)d_in[10];
  const float* bih = (const float*)d_in[11];
  const float* bhh = (const float*)d_in[12];
  const float* Wf1 = (const float*)d_in[13];
  const float* bf1 = (const float*)d_in[14];
  const float* Wf2 = (const float*)d_in[15];
  const float* bf2 = (const float*)d_in[16];
  const float* Wc  = (const float*)d_in[17];
  const float* bc  = (const float*)d_in[18];
  float* out = (float*)d_out;

  // ---- workspace layout (peak ~119 MB) ----
  // [ffout 128KB][ U: union of
  //    LSTM phase: gates 64MB | h 16MB | c 16MB                (100.7 MB)
  //    GCN phase:  sn,dn,Mg 9.4MB | A 92.3MB | T 11.5MB | Y3 5.8MB (119 MB) ]
  char* ws = (char*)d_ws;
  float* ffout = (float*)ws;
  char*  U     = ws + 131072;
  // LSTM phase
  float* gates = (float*)U;
  float* hbuf  = (float*)(U + 67108864);
  float* cbuf  = (float*)(U + 67108864 + 16777216);
  // GCN phase (reuses U after LSTM completes in-stream)
  float* sn    = (float*)U;
  float* dn    = sn + NTOT;
  float* Mg    = dn + NTOT;
  bf16*  Abuf  = (bf16*)(U + 9371648);                       // 92,274,688 B
  bf16*  Tbuf  = (bf16*)(U + 9371648 + 92274688);            // 11,534,336 B
  float* Y3    = (float*)(U + 9371648 + 92274688 + 11534336);// 5,767,168 B

  // ================= LSTM branch =================
  hipMemsetAsync(hbuf, 0, 2 * 16777216, stream);   // h and c -> 0
  for (int t = 0; t < NPG; ++t) {
    gemm_lstm<<<dim3(16, 256), 256, 0, stream>>>(feature, hbuf, Wih, Whh, gates, t);
    lstm_pointwise<<<BG, 256, 0, stream>>>(gates, bih, bhh, hbuf, cbuf);
  }
  ff_kernel<<<BG, 64, 0, stream>>>(hbuf, Wf1, bf1, Wf2, bf2, ffout);

  // ================= GCN branch =================
  hipMemsetAsync(sn, 0, 9371648, stream);          // sn, dn, Mg -> 0
  k_edge_deg<<<EDG / 256, 256, 0, stream>>>(src, dst, sn, dn);
  k_norms<<<(2 * NTOT) / 256, 256, 0, stream>>>(sn);
  k_build_M<<<EDG / 256, 256, 0, stream>>>(src, dst, sn, dn, Mg);

  // layer 1: full GEMM into A, then in-place graph mix + relu
  gemm_nn<float, bf16><<<dim3(4, NTOT / 64), 256, 0, stream>>>(feature, W1, Abuf, 256, 256);
  k_mapply<0><<<BG, 256, 0, stream>>>(Abuf, Mg, b1, Abuf, 0);

  // layer 2: chunked GEMM through bounce buffer T, mix+tanh back into A
  for (int ch = 0; ch < BG; ch += CHG) {
    const bf16* Ain = Abuf + (size_t)ch * NPG * 256;
    gemm_nn<bf16, bf16><<<dim3(4, CHR / 64), 256, 0, stream>>>(Ain, W2, Tbuf, 256, 256);
    k_mapply<1><<<CHG, 256, 0, stream>>>(Tbuf, Mg, b2, Abuf + (size_t)ch * NPG * 256, ch);
  }

  // layer 3 + pooling + classifier + combine
  k_gemm3<<<NTOT / 32, 256, 0, stream>>>(Abuf, W3, Y3);
  k_final<<<BG / 32, 256, 0, stream>>>(Y3, Mg, b3, Wc, bc, ffout, out);
}

// Round 3
// 1219.409 us; speedup vs baseline: 3.4847x; 3.4847x over previous
//
#include <hip/hip_runtime.h>
#include <hip/hip_bf16.h>
#include <type_traits>

using u16 = unsigned short;

static constexpr int BG   = 16384;          // graphs
static constexpr int NPG  = 11;             // nodes per graph
static constexpr int NTOT = BG * NPG;       // 180224 nodes
static constexpr int EDG  = NTOT * 8;       // 1441792 edges

typedef __attribute__((ext_vector_type(8))) short short8;   // 8 bf16 (4 VGPRs)
typedef __attribute__((ext_vector_type(4))) float f32x4;

__device__ __forceinline__ u16 f2bf(float f) {              // RNE fp32->bf16
  unsigned u = __float_as_uint(f);
  return (u16)((u + 0x7FFFu + ((u >> 16) & 1u)) >> 16);
}
__device__ __forceinline__ float bf2f(u16 u) { return __uint_as_float(((unsigned)u) << 16); }
__device__ __forceinline__ unsigned pk(float a, float b) {
  return (unsigned)f2bf(a) | ((unsigned)f2bf(b) << 16);
}

// ---------------------------------------------------------------------------
// MFMA GEMM: C[M,N] = A[M,K] @ Bt[N,K]^T.  BM=128, BN=256, BK=32, 512 thr.
// AMODE 0: A fp32 row-major (stride K), convert to bf16 on stage.
// AMODE 1: A bf16 row-major (stride K). In-place C==A is safe (row-block
//          reads complete before epilogue writes; column dim covered fully).
// AMODE 2: LSTM concat: k<256 from fp32 feature (stride 2816, +tstep*256),
//          k>=256 from bf16 h (stride 256).
// LDS 16B-unit swizzle: slot = (k/8) ^ (row&3)  -> 2-way max on read+write.
// ---------------------------------------------------------------------------
template<int AMODE, typename TC>
__global__ __launch_bounds__(512) void gemm_mfma(const float* __restrict__ Af,
                                                 const u16* Ab,
                                                 const u16* __restrict__ Bt,
                                                 TC* C, int N, int K, int tstep) {
  __shared__ u16 Alds[128 * 32];
  __shared__ u16 Blds[256 * 32];
  const int tid  = threadIdx.x;
  const int lane = tid & 63;
  const int wave = tid >> 6;
  const int q = lane >> 4;            // quad: k-offset q*8 in fragments
  const int l = lane & 15;
  const int wm = (wave >> 2) * 64;    // 2x4 wave grid over 128x256
  const int wn = (wave & 3) * 64;
  const int row0 = blockIdx.y * 128;
  const int col0 = blockIdx.x * 256;

  f32x4 acc[4][4] = {};

  const int sr = tid >> 2;            // 0..127: A row / B row (i*128+)
  const int sq = tid & 3;             // k-slot 0..3 (8 elems each)
  const int aslot = sq ^ (sr & 3);

  for (int k0 = 0; k0 < K; k0 += 32) {
    // ---- stage A tile (128 x 32) ----
    {
      uint4 v;
      if constexpr (AMODE == 0) {
        const float* p = Af + (size_t)(row0 + sr) * K + k0 + sq * 8;
        float4 f0 = *(const float4*)p;
        float4 f1 = *(const float4*)(p + 4);
        v.x = pk(f0.x, f0.y); v.y = pk(f0.z, f0.w);
        v.z = pk(f1.x, f1.y); v.w = pk(f1.z, f1.w);
      } else if constexpr (AMODE == 1) {
        v = *(const uint4*)(Ab + (size_t)(row0 + sr) * K + k0 + sq * 8);
      } else {
        if (k0 < 256) {
          const float* p = Af + (size_t)(row0 + sr) * 2816 + tstep * 256 + k0 + sq * 8;
          float4 f0 = *(const float4*)p;
          float4 f1 = *(const float4*)(p + 4);
          v.x = pk(f0.x, f0.y); v.y = pk(f0.z, f0.w);
          v.z = pk(f1.x, f1.y); v.w = pk(f1.z, f1.w);
        } else {
          v = *(const uint4*)(Ab + (size_t)(row0 + sr) * 256 + (k0 - 256) + sq * 8);
        }
      }
      *(uint4*)&Alds[(((sr << 2) + aslot)) << 3] = v;
    }
    // ---- stage B tile (256 x 32) ----
    #pragma unroll
    for (int i = 0; i < 2; ++i) {
      const int n = sr + i * 128;
      const int slot = sq ^ (n & 3);
      uint4 v = *(const uint4*)(Bt + (size_t)(col0 + n) * K + k0 + sq * 8);
      *(uint4*)&Blds[(((n << 2) + slot)) << 3] = v;
    }
    __syncthreads();
    // ---- fragments + 16 MFMA ----
    short8 af[4], bfr[4];
    #pragma unroll
    for (int i = 0; i < 4; ++i) {
      const int r = wm + i * 16 + l;
      af[i] = *(const short8*)&Alds[(((r << 2) + (q ^ (r & 3)))) << 3];
    }
    #pragma unroll
    for (int j = 0; j < 4; ++j) {
      const int n = wn + j * 16 + l;
      bfr[j] = *(const short8*)&Blds[(((n << 2) + (q ^ (n & 3)))) << 3];
    }
    #pragma unroll
    for (int i = 0; i < 4; ++i)
      #pragma unroll
      for (int j = 0; j < 4; ++j)
        acc[i][j] = __builtin_amdgcn_mfma_f32_16x16x32_bf16(af[i], bfr[j], acc[i][j], 0, 0, 0);
    __syncthreads();
  }
  // ---- epilogue: C/D layout col=lane&15, row=quad*4+reg ----
  #pragma unroll
  for (int i = 0; i < 4; ++i) {
    #pragma unroll
    for (int j = 0; j < 4; ++j) {
      #pragma unroll
      for (int r = 0; r < 4; ++r) {
        const int row = row0 + wm + i * 16 + q * 4 + r;
        const int col = col0 + wn + j * 16 + l;
        if constexpr (std::is_same<TC, float>::value)
          C[(size_t)row * N + col] = acc[i][j][r];
        else
          C[(size_t)row * N + col] = f2bf(acc[i][j][r]);
      }
    }
  }
}

// ---------------- weight prep ----------------
__global__ __launch_bounds__(256) void k_prep_lstm_w(const float* __restrict__ Wih,
                                                     const float* __restrict__ Whh,
                                                     u16* __restrict__ Wcomb) {
  const int idx = blockIdx.x * 256 + threadIdx.x;   // 1024*512
  const int n = idx >> 9, k = idx & 511;
  const float v = (k < 256) ? Wih[n * 256 + k] : Whh[n * 256 + (k - 256)];
  Wcomb[idx] = f2bf(v);
}

__global__ __launch_bounds__(256) void k_transpose_w(const float* __restrict__ W,
                                                     u16* __restrict__ Wt) {
  const int idx = blockIdx.x * 256 + threadIdx.x;   // 256*256, Wt[n][k]=W[k][n]
  const int n = idx >> 8, k = idx & 255;
  Wt[idx] = f2bf(W[k * 256 + n]);
}

// gates -> (c,h) update. PyTorch gate order i,f,g,o. h stored bf16.
__global__ __launch_bounds__(256) void lstm_pointwise(const float* __restrict__ gates,
                                                      const float* __restrict__ bih,
                                                      const float* __restrict__ bhh,
                                                      u16* __restrict__ h,
                                                      float* __restrict__ c) {
  const int idx = blockIdx.x * 256 + threadIdx.x;
  const int b = idx >> 8, u = idx & 255;
  const float* gp = gates + (size_t)b * 1024;
  float gi = gp[u]       + bih[u]       + bhh[u];
  float gf = gp[256 + u] + bih[256 + u] + bhh[256 + u];
  float gg = gp[512 + u] + bih[512 + u] + bhh[512 + u];
  float go = gp[768 + u] + bih[768 + u] + bhh[768 + u];
  float si = 1.f / (1.f + __expf(-gi));
  float sf = 1.f / (1.f + __expf(-gf));
  float so = 1.f / (1.f + __expf(-go));
  float cn = sf * c[idx] + si * tanhf(gg);
  c[idx] = cn;
  h[idx] = f2bf(so * tanhf(cn));
}

// out_ff[b,:2] = (h[b] @ Wf1 + bf1) @ Wf2 + bf2
__global__ __launch_bounds__(64) void ff_kernel(const u16* __restrict__ h,
                                                const float* __restrict__ Wf1,
                                                const float* __restrict__ bf1,
                                                const float* __restrict__ Wf2,
                                                const float* __restrict__ bf2,
                                                float* __restrict__ ffout) {
  __shared__ float hrow[256];
  __shared__ float tmp[64];
  const int b = blockIdx.x, tid = threadIdx.x;
  for (int k = tid; k < 256; k += 64) hrow[k] = bf2f(h[(size_t)b * 256 + k]);
  __syncthreads();
  float acc = bf1[tid];
  #pragma unroll 8
  for (int k = 0; k < 256; ++k) acc += hrow[k] * Wf1[k * 64 + tid];
  tmp[tid] = acc;
  __syncthreads();
  if (tid < 2) {
    float o = bf2[tid];
    #pragma unroll
    for (int j = 0; j < 64; ++j) o += tmp[j] * Wf2[j * 2 + tid];
    ffout[(size_t)b * 2 + tid] = o;
  }
}

// ---------------- GCN graph-operator precompute ----------------
__global__ __launch_bounds__(256) void k_edge_deg(const int* __restrict__ src,
                                                  const int* __restrict__ dst,
                                                  float* __restrict__ odeg,
                                                  float* __restrict__ ideg) {
  const int e = blockIdx.x * 256 + threadIdx.x;
  atomicAdd(&odeg[src[e]], 1.0f);
  atomicAdd(&ideg[dst[e]], 1.0f);
}

__global__ __launch_bounds__(256) void k_norms(float* __restrict__ d) {
  const int i = blockIdx.x * 256 + threadIdx.x;   // covers sn and dn
  d[i] = rsqrtf(fmaxf(d[i], 1.0f));
}

__global__ __launch_bounds__(256) void k_build_M(const int* __restrict__ src,
                                                 const int* __restrict__ dst,
                                                 const float* __restrict__ sn,
                                                 const float* __restrict__ dn,
                                                 float* __restrict__ Mg) {
  const int e = blockIdx.x * 256 + threadIdx.x;
  const int s = src[e], d = dst[e];
  const int g = s / NPG;
  const int ls = s - g * NPG;
  const int ld = d - g * NPG;
  atomicAdd(&Mg[(size_t)g * 121 + ld * NPG + ls], sn[s] * dn[d]);
}

// X[g,d,:] = act( sum_s M_g[d][s] * Y[g,s,:] + bias )  in-place safe
template<int ACT>
__global__ __launch_bounds__(256) void k_mapply(const u16* __restrict__ Y,
                                                const float* __restrict__ Mg,
                                                const float* __restrict__ bias,
                                                u16* __restrict__ X) {
  __shared__ float Ms[121];
  const int g = blockIdx.x, c = threadIdx.x;
  if (c < 121) Ms[c] = Mg[(size_t)g * 121 + c];
  float y[NPG];
  const u16* yp = Y + (size_t)g * NPG * 256 + c;
  #pragma unroll
  for (int s = 0; s < NPG; ++s) y[s] = bf2f(yp[s * 256]);
  const float bc_ = bias[c];
  __syncthreads();
  u16* xp = X + (size_t)g * NPG * 256 + c;
  #pragma unroll
  for (int d = 0; d < NPG; ++d) {
    float z = bc_;
    #pragma unroll
    for (int s = 0; s < NPG; ++s) z += Ms[d * NPG + s] * y[s];
    if (ACT == 0) z = fmaxf(z, 0.f); else z = tanhf(z);
    xp[d * 256] = f2bf(z);
  }
}

// Y3[N,8] = X[N,256] @ W3[256,8]
__global__ __launch_bounds__(256) void k_gemm3(const u16* __restrict__ X,
                                               const float* __restrict__ W3,
                                               float* __restrict__ Y3) {
  __shared__ float W3s[2048];
  const int tid = threadIdx.x;
  for (int i = tid; i < 2048; i += 256) W3s[i] = W3[i];
  __syncthreads();
  const int r = tid >> 3, j = tid & 7;
  const int row = blockIdx.x * 32 + r;
  const u16* xp = X + (size_t)row * 256;
  float acc = 0.f;
  #pragma unroll 4
  for (int k = 0; k < 256; ++k) acc += bf2f(xp[k]) * W3s[k * 8 + j];
  Y3[(size_t)row * 8 + j] = acc;
}

// layer3 M-apply + relu + mean + classify + add LSTM ff output
__global__ __launch_bounds__(256) void k_final(const float* __restrict__ Y3,
                                               const float* __restrict__ Mg,
                                               const float* __restrict__ b3,
                                               const float* __restrict__ Wc,
                                               const float* __restrict__ bc,
                                               const float* __restrict__ ffout,
                                               float* __restrict__ out) {
  __shared__ float Ms[32][121];
  __shared__ float hg[32][8];
  const int tid = threadIdx.x;
  const int g0 = blockIdx.x * 32;
  for (int i = tid; i < 32 * 121; i += 256) Ms[i / 121][i % 121] = Mg[(size_t)g0 * 121 + i];
  const int gl = tid >> 3, j = tid & 7;
  const int g = g0 + gl;
  float y[NPG];
  #pragma unroll
  for (int s = 0; s < NPG; ++s) y[s] = Y3[((size_t)g * NPG + s) * 8 + j];
  __syncthreads();
  const float bj = b3[j];
  float accm = 0.f;
  #pragma unroll
  for (int d = 0; d < NPG; ++d) {
    float z = bj;
    #pragma unroll
    for (int s = 0; s < NPG; ++s) z += Ms[gl][d * NPG + s] * y[s];
    accm += fmaxf(z, 0.f);
  }
  hg[gl][j] = accm * (1.0f / 11.0f);
  __syncthreads();
  if (j < 2) {
    float o = bc[j];
    #pragma unroll
    for (int q = 0; q < 8; ++q) o += hg[gl][q] * Wc[q * 2 + j];
    out[(size_t)g * 2 + j] = o + ffout[(size_t)g * 2 + j];
  }
}

// ---------------------------------------------------------------------------
extern "C" void kernel_launch(void* const* d_in, const int* in_sizes, int n_in,
                              void* d_out, int out_size, void* d_ws, size_t ws_size,
                              hipStream_t stream) {
  (void)in_sizes; (void)n_in; (void)out_size; (void)ws_size;
  const float* feature = (const float*)d_in[0];
  const int*   src     = (const int*)d_in[1];
  const int*   dst     = (const int*)d_in[2];
  const float* W1  = (const float*)d_in[3];
  const float* b1  = (const float*)d_in[4];
  const float* W2  = (const float*)d_in[5];
  const float* b2  = (const float*)d_in[6];
  const float* W3  = (const float*)d_in[7];
  const float* b3  = (const float*)d_in[8];
  const float* Wih = (const float*)d_in[9];
  const float* Whh = (const float*)d_in[10];
  const float* bih = (const float*)d_in[11];
  const float* bhh = (const float*)d_in[12];
  const float* Wf1 = (const float*)d_in[13];
  const float* bf1 = (const float*)d_in[14];
  const float* Wf2 = (const float*)d_in[15];
  const float* bf2 = (const float*)d_in[16];
  const float* Wc  = (const float*)d_in[17];
  const float* bc  = (const float*)d_in[18];
  float* out = (float*)d_out;

  // ---- workspace layout (peak ~109 MB) ----
  // [ffout 128K][Wcomb 1M][Wt1 128K][Wt2 128K][ U: union of
  //   LSTM: gates 64M | h(bf16) 8M | c 16M            (92.3 MB)
  //   GCN:  sn,dn,Mg 9.4M | Abuf(bf16) 92.3M | Y3 5.8M (107.4 MB) ]
  char* ws = (char*)d_ws;
  float* ffout = (float*)ws;
  u16*   Wcomb = (u16*)(ws + 131072);
  u16*   Wt1   = (u16*)(ws + 131072 + 1048576);
  u16*   Wt2   = (u16*)(ws + 131072 + 1048576 + 131072);
  char*  U     = ws + 1441792;
  // LSTM phase
  float* gates = (float*)U;                             // 67,108,864
  u16*   hbuf  = (u16*)(U + 67108864);                  //  8,388,608
  float* cbuf  = (float*)(U + 67108864 + 8388608);      // 16,777,216
  // GCN phase (reuses U after LSTM completes in-stream)
  float* sn    = (float*)U;
  float* dn    = sn + NTOT;
  float* Mg    = dn + NTOT;
  u16*   Abuf  = (u16*)(U + 9371648);                   // 92,274,688
  float* Y3    = (float*)(U + 9371648 + 92274688);      //  5,767,168

  // ---- weight prep ----
  k_prep_lstm_w<<<2048, 256, 0, stream>>>(Wih, Whh, Wcomb);
  k_transpose_w<<<256, 256, 0, stream>>>(W1, Wt1);
  k_transpose_w<<<256, 256, 0, stream>>>(W2, Wt2);

  // ================= LSTM branch =================
  hipMemsetAsync(hbuf, 0, 8388608 + 16777216, stream);   // h, c -> 0
  for (int t = 0; t < NPG; ++t) {
    gemm_mfma<2, float><<<dim3(4, 128), 512, 0, stream>>>(feature, hbuf, Wcomb, gates, 1024, 512, t);
    lstm_pointwise<<<BG, 256, 0, stream>>>(gates, bih, bhh, hbuf, cbuf);
  }
  ff_kernel<<<BG, 64, 0, stream>>>(hbuf, Wf1, bf1, Wf2, bf2, ffout);

  // ================= GCN branch =================
  hipMemsetAsync(sn, 0, 9371648, stream);                // sn, dn, Mg -> 0
  k_edge_deg<<<EDG / 256, 256, 0, stream>>>(src, dst, sn, dn);
  k_norms<<<(2 * NTOT) / 256, 256, 0, stream>>>(sn);
  k_build_M<<<EDG / 256, 256, 0, stream>>>(src, dst, sn, dn, Mg);

  // layer 1: GEMM (fp32 A -> bf16) + in-place graph mix + relu
  gemm_mfma<0, u16><<<dim3(1, NTOT / 128), 512, 0, stream>>>(feature, nullptr, Wt1, Abuf, 256, 256, 0);
  k_mapply<0><<<BG, 256, 0, stream>>>(Abuf, Mg, b1, Abuf);

  // layer 2: in-place GEMM (full N covered per row-block) + mix + tanh
  gemm_mfma<1, u16><<<dim3(1, NTOT / 128), 512, 0, stream>>>(nullptr, Abuf, Wt2, Abuf, 256, 256, 0);
  k_mapply<1><<<BG, 256, 0, stream>>>(Abuf, Mg, b2, Abuf);

  // layer 3 + pooling + classifier + combine
  k_gemm3<<<NTOT / 32, 256, 0, stream>>>(Abuf, W3, Y3);
  k_final<<<BG / 32, 256, 0, stream>>>(Y3, Mg, b3, Wc, bc, ffout, out);
}

// Round 4
// 1159.161 us; speedup vs baseline: 3.6658x; 1.0520x over previous
//
#include <hip/hip_runtime.h>
#include <hip/hip_bf16.h>
#include <type_traits>

using u16 = unsigned short;

static constexpr int BG   = 16384;          // graphs
static constexpr int NPG  = 11;             // nodes per graph
static constexpr int NTOT = BG * NPG;       // 180224 nodes
static constexpr int EDG  = NTOT * 8;       // 1441792 edges

typedef __attribute__((ext_vector_type(8))) short short8;   // 8 bf16 (4 VGPRs)
typedef __attribute__((ext_vector_type(4))) float f32x4;

__device__ __forceinline__ u16 f2bf(float f) {              // RNE fp32->bf16
  unsigned u = __float_as_uint(f);
  return (u16)((u + 0x7FFFu + ((u >> 16) & 1u)) >> 16);
}
__device__ __forceinline__ float bf2f(u16 u) { return __uint_as_float(((unsigned)u) << 16); }
__device__ __forceinline__ unsigned pk(float a, float b) {
  return (unsigned)f2bf(a) | ((unsigned)f2bf(b) << 16);
}
__device__ __forceinline__ float fast_sig(float x) {
  return 1.f / (1.f + __expf(-x));
}
__device__ __forceinline__ float fast_tanh(float x) {       // overflow-safe
  float a = fabsf(x);
  float e = __expf(-2.f * a);
  float t = (1.f - e) / (1.f + e);
  return copysignf(t, x);
}
__device__ __forceinline__ float sel4(float a0, float a1, float a2, float a3, int k) {
  float m01 = (k & 1) ? a1 : a0;
  float m23 = (k & 1) ? a3 : a2;
  return (k & 2) ? m23 : m01;
}

// ---------------------------------------------------------------------------
// Fused LSTM step: gates = [x_t | h] @ Wp^T (+biasP), pointwise, h/c update.
// Wp rows permuted: n' = 4*unit + gate  (gate order i,f,g,o).
// BM=64, BN=1024 (full), BK=32, 512 threads, 8 waves of 64x128.
// Gates live only in AGPR/VGPR; epilogue exchanges the 4 gates of a unit
// within 4-lane groups via shfl_xor, each lane handling row-reg r=lane&3.
// ---------------------------------------------------------------------------
__global__ __launch_bounds__(512) void lstm_fused(const float* __restrict__ feat,
                                                  u16* __restrict__ h,
                                                  float* __restrict__ c,
                                                  const u16* __restrict__ Wp,
                                                  const float* __restrict__ biasP,
                                                  int t) {
  __shared__ u16 Alds[64 * 32];
  __shared__ u16 Blds[1024 * 32];
  const int tid  = threadIdx.x;
  const int lane = tid & 63;
  const int wave = tid >> 6;
  const int q = lane >> 4;
  const int l = lane & 15;
  const int wn = wave * 128;
  const int row0 = blockIdx.x * 64;

  f32x4 acc[4][8] = {};
  const int sq = tid & 3;

  for (int k0 = 0; k0 < 512; k0 += 32) {
    if (tid < 256) {                       // stage A (64 x 32)
      const int sr = tid >> 2;
      uint4 v;
      if (k0 < 256) {
        const float* p = feat + (size_t)(row0 + sr) * 2816 + t * 256 + k0 + sq * 8;
        float4 f0 = *(const float4*)p;
        float4 f1 = *(const float4*)(p + 4);
        v.x = pk(f0.x, f0.y); v.y = pk(f0.z, f0.w);
        v.z = pk(f1.x, f1.y); v.w = pk(f1.z, f1.w);
      } else {
        v = *(const uint4*)(h + (size_t)(row0 + sr) * 256 + (k0 - 256) + sq * 8);
      }
      *(uint4*)&Alds[(((sr << 2) + (sq ^ (sr & 3)))) << 3] = v;
    }
    {                                      // stage B (1024 x 32), 8 rows/thread
      const int br = tid >> 2;             // 0..127
      #pragma unroll
      for (int i = 0; i < 8; ++i) {
        const int n = br + i * 128;
        uint4 v = *(const uint4*)(Wp + (size_t)n * 512 + k0 + sq * 8);
        *(uint4*)&Blds[(((n << 2) + (sq ^ (n & 3)))) << 3] = v;
      }
    }
    __syncthreads();
    short8 af[4], bfr[8];
    #pragma unroll
    for (int i = 0; i < 4; ++i) {
      const int r = i * 16 + l;
      af[i] = *(const short8*)&Alds[(((r << 2) + (q ^ (r & 3)))) << 3];
    }
    #pragma unroll
    for (int j = 0; j < 8; ++j) {
      const int n = wn + j * 16 + l;
      bfr[j] = *(const short8*)&Blds[(((n << 2) + (q ^ (n & 3)))) << 3];
    }
    #pragma unroll
    for (int i = 0; i < 4; ++i)
      #pragma unroll
      for (int j = 0; j < 8; ++j)
        acc[i][j] = __builtin_amdgcn_mfma_f32_16x16x32_bf16(af[i], bfr[j], acc[i][j], 0, 0, 0);
    __syncthreads();
  }

  // ---- epilogue: gate exchange + LSTM pointwise ----
  const int tg = l & 3;                    // this lane's gate index
  #pragma unroll
  for (int i = 0; i < 4; ++i) {
    #pragma unroll
    for (int j = 0; j < 8; ++j) {
      const int col = wn + j * 16 + l;     // = 4*u + tg
      const int u = col >> 2;
      const float bb = biasP[col];
      float gi = 0.f, gf = 0.f, gg = 0.f, go = 0.f;
      #pragma unroll
      for (int r = 0; r < 4; ++r) {
        float v  = acc[i][j][r] + bb;
        float x1 = __shfl_xor(v, 1);
        float x2 = __shfl_xor(v, 2);
        float x3 = __shfl_xor(v, 3);
        // value holding gate G (for row-reg r) came from xor k = G ^ tg
        float cgi = sel4(v, x1, x2, x3, tg);
        float cgf = sel4(v, x1, x2, x3, tg ^ 1);
        float cgg = sel4(v, x1, x2, x3, tg ^ 2);
        float cgo = sel4(v, x1, x2, x3, tg ^ 3);
        const bool mine = (tg == r);       // lane owns row-reg r == its gate idx
        gi = mine ? cgi : gi;
        gf = mine ? cgf : gf;
        gg = mine ? cgg : gg;
        go = mine ? cgo : go;
      }
      const int row = row0 + i * 16 + q * 4 + tg;
      const size_t cidx = (size_t)row * 256 + u;
      float cold = c[cidx];
      float cn = fast_sig(gf) * cold + fast_sig(gi) * fast_tanh(gg);
      c[cidx] = cn;
      h[cidx] = f2bf(fast_sig(go) * fast_tanh(cn));
    }
  }
}

// ---------------------------------------------------------------------------
// MFMA GEMM: C[M,N] = A[M,K] @ Bt[N,K]^T.  BM=128, BN=256, BK=32, 512 thr.
// AMODE 0: A fp32 row-major (stride K). AMODE 1: A bf16 row-major; in-place
// C==A safe (full row read before epilogue write, full N per row-block).
// ---------------------------------------------------------------------------
template<int AMODE, typename TC>
__global__ __launch_bounds__(512) void gemm_mfma(const float* __restrict__ Af,
                                                 const u16* Ab,
                                                 const u16* __restrict__ Bt,
                                                 TC* C, int N, int K) {
  __shared__ u16 Alds[128 * 32];
  __shared__ u16 Blds[256 * 32];
  const int tid  = threadIdx.x;
  const int lane = tid & 63;
  const int wave = tid >> 6;
  const int q = lane >> 4;
  const int l = lane & 15;
  const int wm = (wave >> 2) * 64;
  const int wn = (wave & 3) * 64;
  const int row0 = blockIdx.y * 128;
  const int col0 = blockIdx.x * 256;

  f32x4 acc[4][4] = {};
  const int sr = tid >> 2;
  const int sq = tid & 3;
  const int aslot = sq ^ (sr & 3);

  for (int k0 = 0; k0 < K; k0 += 32) {
    {
      uint4 v;
      if constexpr (AMODE == 0) {
        const float* p = Af + (size_t)(row0 + sr) * K + k0 + sq * 8;
        float4 f0 = *(const float4*)p;
        float4 f1 = *(const float4*)(p + 4);
        v.x = pk(f0.x, f0.y); v.y = pk(f0.z, f0.w);
        v.z = pk(f1.x, f1.y); v.w = pk(f1.z, f1.w);
      } else {
        v = *(const uint4*)(Ab + (size_t)(row0 + sr) * K + k0 + sq * 8);
      }
      *(uint4*)&Alds[(((sr << 2) + aslot)) << 3] = v;
    }
    #pragma unroll
    for (int i = 0; i < 2; ++i) {
      const int n = sr + i * 128;
      const int slot = sq ^ (n & 3);
      uint4 v = *(const uint4*)(Bt + (size_t)(col0 + n) * K + k0 + sq * 8);
      *(uint4*)&Blds[(((n << 2) + slot)) << 3] = v;
    }
    __syncthreads();
    short8 af[4], bfr[4];
    #pragma unroll
    for (int i = 0; i < 4; ++i) {
      const int r = wm + i * 16 + l;
      af[i] = *(const short8*)&Alds[(((r << 2) + (q ^ (r & 3)))) << 3];
    }
    #pragma unroll
    for (int j = 0; j < 4; ++j) {
      const int n = wn + j * 16 + l;
      bfr[j] = *(const short8*)&Blds[(((n << 2) + (q ^ (n & 3)))) << 3];
    }
    #pragma unroll
    for (int i = 0; i < 4; ++i)
      #pragma unroll
      for (int j = 0; j < 4; ++j)
        acc[i][j] = __builtin_amdgcn_mfma_f32_16x16x32_bf16(af[i], bfr[j], acc[i][j], 0, 0, 0);
    __syncthreads();
  }
  #pragma unroll
  for (int i = 0; i < 4; ++i) {
    #pragma unroll
    for (int j = 0; j < 4; ++j) {
      #pragma unroll
      for (int r = 0; r < 4; ++r) {
        const int row = row0 + wm + i * 16 + q * 4 + r;
        const int col = col0 + wn + j * 16 + l;
        if constexpr (std::is_same<TC, float>::value)
          C[(size_t)row * N + col] = acc[i][j][r];
        else
          C[(size_t)row * N + col] = f2bf(acc[i][j][r]);
      }
    }
  }
}

// ---------------- weight prep ----------------
// Wp[n'][k], n' = 4*unit + gate; also builds permuted combined bias.
__global__ __launch_bounds__(256) void k_prep_lstm_w(const float* __restrict__ Wih,
                                                     const float* __restrict__ Whh,
                                                     const float* __restrict__ bih,
                                                     const float* __restrict__ bhh,
                                                     u16* __restrict__ Wp,
                                                     float* __restrict__ biasP) {
  const int idx = blockIdx.x * 256 + threadIdx.x;   // 1024*512
  const int np = idx >> 9, k = idx & 511;
  const int u = np >> 2, g = np & 3;
  const int n = g * 256 + u;
  const float v = (k < 256) ? Wih[n * 256 + k] : Whh[n * 256 + (k - 256)];
  Wp[idx] = f2bf(v);
  if (k == 0) biasP[np] = bih[n] + bhh[n];
}

__global__ __launch_bounds__(256) void k_transpose_w(const float* __restrict__ W,
                                                     u16* __restrict__ Wt) {
  const int idx = blockIdx.x * 256 + threadIdx.x;   // 256*256, Wt[n][k]=W[k][n]
  const int n = idx >> 8, k = idx & 255;
  Wt[idx] = f2bf(W[k * 256 + n]);
}

// out_ff[b,:2] = (h[b] @ Wf1 + bf1) @ Wf2 + bf2
__global__ __launch_bounds__(64) void ff_kernel(const u16* __restrict__ h,
                                                const float* __restrict__ Wf1,
                                                const float* __restrict__ bf1,
                                                const float* __restrict__ Wf2,
                                                const float* __restrict__ bf2,
                                                float* __restrict__ ffout) {
  __shared__ float hrow[256];
  __shared__ float tmp[64];
  const int b = blockIdx.x, tid = threadIdx.x;
  for (int k = tid; k < 256; k += 64) hrow[k] = bf2f(h[(size_t)b * 256 + k]);
  __syncthreads();
  float acc = bf1[tid];
  #pragma unroll 8
  for (int k = 0; k < 256; ++k) acc += hrow[k] * Wf1[k * 64 + tid];
  tmp[tid] = acc;
  __syncthreads();
  if (tid < 2) {
    float o = bf2[tid];
    #pragma unroll
    for (int j = 0; j < 64; ++j) o += tmp[j] * Wf2[j * 2 + tid];
    ffout[(size_t)b * 2 + tid] = o;
  }
}

// ---------------- GCN graph-operator precompute ----------------
__global__ __launch_bounds__(256) void k_edge_deg(const int* __restrict__ src,
                                                  const int* __restrict__ dst,
                                                  float* __restrict__ odeg,
                                                  float* __restrict__ ideg) {
  const int e = blockIdx.x * 256 + threadIdx.x;
  atomicAdd(&odeg[src[e]], 1.0f);
  atomicAdd(&ideg[dst[e]], 1.0f);
}

__global__ __launch_bounds__(256) void k_norms(float* __restrict__ d) {
  const int i = blockIdx.x * 256 + threadIdx.x;   // covers sn and dn
  d[i] = rsqrtf(fmaxf(d[i], 1.0f));
}

__global__ __launch_bounds__(256) void k_build_M(const int* __restrict__ src,
                                                 const int* __restrict__ dst,
                                                 const float* __restrict__ sn,
                                                 const float* __restrict__ dn,
                                                 float* __restrict__ Mg) {
  const int e = blockIdx.x * 256 + threadIdx.x;
  const int s = src[e], d = dst[e];
  const int g = s / NPG;
  const int ls = s - g * NPG;
  const int ld = d - g * NPG;
  atomicAdd(&Mg[(size_t)g * 121 + ld * NPG + ls], sn[s] * dn[d]);
}

// X[g,d,:] = act( sum_s M_g[d][s] * Y[g,s,:] + bias )  in-place safe
template<int ACT>
__global__ __launch_bounds__(256) void k_mapply(const u16* __restrict__ Y,
                                                const float* __restrict__ Mg,
                                                const float* __restrict__ bias,
                                                u16* __restrict__ X) {
  __shared__ float Ms[121];
  const int g = blockIdx.x, c = threadIdx.x;
  if (c < 121) Ms[c] = Mg[(size_t)g * 121 + c];
  float y[NPG];
  const u16* yp = Y + (size_t)g * NPG * 256 + c;
  #pragma unroll
  for (int s = 0; s < NPG; ++s) y[s] = bf2f(yp[s * 256]);
  const float bc_ = bias[c];
  __syncthreads();
  u16* xp = X + (size_t)g * NPG * 256 + c;
  #pragma unroll
  for (int d = 0; d < NPG; ++d) {
    float z = bc_;
    #pragma unroll
    for (int s = 0; s < NPG; ++s) z += Ms[d * NPG + s] * y[s];
    if (ACT == 0) z = fmaxf(z, 0.f); else z = fast_tanh(z);
    xp[d * 256] = f2bf(z);
  }
}

// Y3[N,8] = X[N,256] @ W3[256,8]
__global__ __launch_bounds__(256) void k_gemm3(const u16* __restrict__ X,
                                               const float* __restrict__ W3,
                                               float* __restrict__ Y3) {
  __shared__ float W3s[2048];
  const int tid = threadIdx.x;
  for (int i = tid; i < 2048; i += 256) W3s[i] = W3[i];
  __syncthreads();
  const int r = tid >> 3, j = tid & 7;
  const int row = blockIdx.x * 32 + r;
  const u16* xp = X + (size_t)row * 256;
  float acc = 0.f;
  #pragma unroll 4
  for (int k = 0; k < 256; ++k) acc += bf2f(xp[k]) * W3s[k * 8 + j];
  Y3[(size_t)row * 8 + j] = acc;
}

// layer3 M-apply + relu + mean + classify + add LSTM ff output
__global__ __launch_bounds__(256) void k_final(const float* __restrict__ Y3,
                                               const float* __restrict__ Mg,
                                               const float* __restrict__ b3,
                                               const float* __restrict__ Wc,
                                               const float* __restrict__ bc,
                                               const float* __restrict__ ffout,
                                               float* __restrict__ out) {
  __shared__ float Ms[32][121];
  __shared__ float hg[32][8];
  const int tid = threadIdx.x;
  const int g0 = blockIdx.x * 32;
  for (int i = tid; i < 32 * 121; i += 256) Ms[i / 121][i % 121] = Mg[(size_t)g0 * 121 + i];
  const int gl = tid >> 3, j = tid & 7;
  const int g = g0 + gl;
  float y[NPG];
  #pragma unroll
  for (int s = 0; s < NPG; ++s) y[s] = Y3[((size_t)g * NPG + s) * 8 + j];
  __syncthreads();
  const float bj = b3[j];
  float accm = 0.f;
  #pragma unroll
  for (int d = 0; d < NPG; ++d) {
    float z = bj;
    #pragma unroll
    for (int s = 0; s < NPG; ++s) z += Ms[gl][d * NPG + s] * y[s];
    accm += fmaxf(z, 0.f);
  }
  hg[gl][j] = accm * (1.0f / 11.0f);
  __syncthreads();
  if (j < 2) {
    float o = bc[j];
    #pragma unroll
    for (int q = 0; q < 8; ++q) o += hg[gl][q] * Wc[q * 2 + j];
    out[(size_t)g * 2 + j] = o + ffout[(size_t)g * 2 + j];
  }
}

// ---------------------------------------------------------------------------
extern "C" void kernel_launch(void* const* d_in, const int* in_sizes, int n_in,
                              void* d_out, int out_size, void* d_ws, size_t ws_size,
                              hipStream_t stream) {
  (void)in_sizes; (void)n_in; (void)out_size; (void)ws_size;
  const float* feature = (const float*)d_in[0];
  const int*   src     = (const int*)d_in[1];
  const int*   dst     = (const int*)d_in[2];
  const float* W1  = (const float*)d_in[3];
  const float* b1  = (const float*)d_in[4];
  const float* W2  = (const float*)d_in[5];
  const float* b2  = (const float*)d_in[6];
  const float* W3  = (const float*)d_in[7];
  const float* b3  = (const float*)d_in[8];
  const float* Wih = (const float*)d_in[9];
  const float* Whh = (const float*)d_in[10];
  const float* bih = (const float*)d_in[11];
  const float* bhh = (const float*)d_in[12];
  const float* Wf1 = (const float*)d_in[13];
  const float* bf1 = (const float*)d_in[14];
  const float* Wf2 = (const float*)d_in[15];
  const float* bf2 = (const float*)d_in[16];
  const float* Wc  = (const float*)d_in[17];
  const float* bc  = (const float*)d_in[18];
  float* out = (float*)d_out;

  // ---- workspace layout (peak ~109 MB) ----
  // [ffout 128K][Wp 1M][Wt1 128K][Wt2 128K][biasP 4K][ U: union of
  //   LSTM: h(bf16) 8M | c 16M                         (25 MB)
  //   GCN:  sn,dn,Mg 9.4M | Abuf(bf16) 92.3M | Y3 5.8M (107.4 MB) ]
  char* ws = (char*)d_ws;
  float* ffout = (float*)ws;
  u16*   Wp    = (u16*)(ws + 131072);
  u16*   Wt1   = (u16*)(ws + 131072 + 1048576);
  u16*   Wt2   = (u16*)(ws + 131072 + 1048576 + 131072);
  float* biasP = (float*)(ws + 131072 + 1048576 + 131072 + 131072);
  char*  U     = ws + 1572864;
  // LSTM phase
  u16*   hbuf  = (u16*)U;                               //  8,388,608
  float* cbuf  = (float*)(U + 8388608);                 // 16,777,216
  // GCN phase (reuses U after LSTM completes in-stream)
  float* sn    = (float*)U;
  float* dn    = sn + NTOT;
  float* Mg    = dn + NTOT;
  u16*   Abuf  = (u16*)(U + 9371648);                   // 92,274,688
  float* Y3    = (float*)(U + 9371648 + 92274688);      //  5,767,168

  // ---- weight prep ----
  k_prep_lstm_w<<<2048, 256, 0, stream>>>(Wih, Whh, bih, bhh, Wp, biasP);
  k_transpose_w<<<256, 256, 0, stream>>>(W1, Wt1);
  k_transpose_w<<<256, 256, 0, stream>>>(W2, Wt2);

  // ================= LSTM branch =================
  hipMemsetAsync(hbuf, 0, 8388608 + 16777216, stream);   // h, c -> 0
  for (int t = 0; t < NPG; ++t)
    lstm_fused<<<BG / 64, 512, 0, stream>>>(feature, hbuf, cbuf, Wp, biasP, t);
  ff_kernel<<<BG, 64, 0, stream>>>(hbuf, Wf1, bf1, Wf2, bf2, ffout);

  // ================= GCN branch =================
  hipMemsetAsync(sn, 0, 9371648, stream);                // sn, dn, Mg -> 0
  k_edge_deg<<<EDG / 256, 256, 0, stream>>>(src, dst, sn, dn);
  k_norms<<<(2 * NTOT) / 256, 256, 0, stream>>>(sn);
  k_build_M<<<EDG / 256, 256, 0, stream>>>(src, dst, sn, dn, Mg);

  // layer 1: GEMM (fp32 A -> bf16) + in-place graph mix + relu
  gemm_mfma<0, u16><<<dim3(1, NTOT / 128), 512, 0, stream>>>(feature, nullptr, Wt1, Abuf, 256, 256);
  k_mapply<0><<<BG, 256, 0, stream>>>(Abuf, Mg, b1, Abuf);

  // layer 2: in-place GEMM (full N covered per row-block) + mix + tanh
  gemm_mfma<1, u16><<<dim3(1, NTOT / 128), 512, 0, stream>>>(nullptr, Abuf, Wt2, Abuf, 256, 256);
  k_mapply<1><<<BG, 256, 0, stream>>>(Abuf, Mg, b2, Abuf);

  // layer 3 + pooling + classifier + combine
  k_gemm3<<<NTOT / 32, 256, 0, stream>>>(Abuf, W3, Y3);
  k_final<<<BG / 32, 256, 0, stream>>>(Y3, Mg, b3, Wc, bc, ffout, out);
}